// Round 1
// baseline (1938.128 us; speedup 1.0000x reference)
//
#include <hip/hip_runtime.h>
#include <hip/hip_bf16.h>

typedef __hip_bfloat16 bf16;
using bf16x8 = __attribute__((ext_vector_type(8))) short;
using f32x4  = __attribute__((ext_vector_type(4))) float;

#define S_LEN 1024
#define CDIM  576
#define NHEAD 8
#define DKH   72
#define BATCH 4
#define MROWS 4096   // B*S
#define FFDIM 2304

// ---------------- weight transpose + fp32->bf16 convert ----------------
// in: [L, K, N] fp32  ->  out: [L, N, K] bf16   (grid.z = L)
__global__ __launch_bounds__(256) void transpose_cvt(
    const float* __restrict__ in, bf16* __restrict__ out, int K, int N) {
  __shared__ float tile[32][33];
  const size_t mat = (size_t)K * N;
  const float* inl = in + (size_t)blockIdx.z * mat;
  bf16* outl = out + (size_t)blockIdx.z * mat;
  int n0 = blockIdx.x * 32, k0 = blockIdx.y * 32;
  int tx = threadIdx.x & 31, ty = threadIdx.x >> 5;   // ty 0..7
#pragma unroll
  for (int i = 0; i < 32; i += 8)
    tile[ty + i][tx] = inl[(size_t)(k0 + ty + i) * N + (n0 + tx)];
  __syncthreads();
#pragma unroll
  for (int i = 0; i < 32; i += 8)
    outl[(size_t)(n0 + ty + i) * K + (k0 + tx)] = __float2bfloat16(tile[tx][ty + i]);
}

// ---------------- xf = right_shift(x) + pos ----------------
__global__ __launch_bounds__(256) void build_xf(
    const float* __restrict__ x, const float* __restrict__ p0,
    const float* __restrict__ p1, const float* __restrict__ p2,
    float* __restrict__ xf) {
  int idx = blockIdx.x * 256 + threadIdx.x;      // one float4 per thread
  int c4 = idx % 144;
  int s  = (idx / 144) & (S_LEN - 1);
  int b  = idx / (144 * S_LEN);
  int c  = c4 * 4;
  int t = s >> 8, hh = (s >> 4) & 15, w = s & 15;
  float4 pv;
  if (c < 192)       pv = *(const float4*)&p0[t  * 192 + c];
  else if (c < 384)  pv = *(const float4*)&p1[hh * 192 + c - 192];
  else               pv = *(const float4*)&p2[w  * 192 + c - 384];
  float4 xv = make_float4(0.f, 0.f, 0.f, 0.f);
  if (s > 0) xv = *(const float4*)&x[((size_t)b * S_LEN + s - 1) * CDIM + c];
  float4 r = make_float4(xv.x + pv.x, xv.y + pv.y, xv.z + pv.z, xv.w + pv.w);
  *(float4*)&xf[((size_t)b * S_LEN + s) * CDIM + c] = r;
}

// ---------------- LayerNorm (eps added to rsqrt, per reference) ----------------
// one wave per row; block = 4 rows
__global__ __launch_bounds__(256) void ln_kernel(
    const float* __restrict__ x, const float* __restrict__ g,
    const float* __restrict__ b, bf16* __restrict__ out) {
  int row  = blockIdx.x * 4 + (threadIdx.x >> 6);
  int lane = threadIdx.x & 63;
  const float* xr = x + (size_t)row * CDIM;
  float vals[9];
  float sum = 0.f;
#pragma unroll
  for (int i = 0; i < 9; i++) { vals[i] = xr[lane + 64 * i]; sum += vals[i]; }
#pragma unroll
  for (int o = 1; o < 64; o <<= 1) sum += __shfl_xor(sum, o);
  float mu = sum * (1.f / CDIM);
  float vs = 0.f;
#pragma unroll
  for (int i = 0; i < 9; i++) { float d = vals[i] - mu; vs += d * d; }
#pragma unroll
  for (int o = 1; o < 64; o <<= 1) vs += __shfl_xor(vs, o);
  float mult = 1e-5f + rsqrtf(vs * (1.f / CDIM));
  bf16* orow = out + (size_t)row * CDIM;
#pragma unroll
  for (int i = 0; i < 9; i++) {
    int c = lane + 64 * i;
    orow[c] = __float2bfloat16((vals[i] - mu) * mult * g[c] + b[c]);
  }
}

// ---------------- generic bf16 MFMA GEMM ----------------
// C[M,N] = act(A[M,K] @ Bt[N,K]^T + bias) (+ res);  out fp32 or bf16
template <bool BIAS, bool RES, int ACT, bool OUTBF>
__global__ __launch_bounds__(256) void gemm_kernel(
    const bf16* __restrict__ A, const bf16* __restrict__ Bt,
    const float* __restrict__ bias, const float* __restrict__ res,
    void* __restrict__ outp, int M, int N, int K) {
  __shared__ short ldsA[64][40];
  __shared__ short ldsB[64][40];
  int m0 = blockIdx.x * 64, n0 = blockIdx.y * 64;
  int tid = threadIdx.x;
  int wave = tid >> 6, lane = tid & 63;
  int wm = (wave & 1) * 32, wn = (wave >> 1) * 32;
  int lrow = lane & 15, lq = lane >> 4;
  f32x4 acc[2][2] = {};
  int srow = tid >> 2, skc = (tid & 3) * 8;
  const short* Ag = ((const short*)A) + (size_t)(m0 + srow) * K + skc;
  const short* Bg = ((const short*)Bt) + (size_t)(n0 + srow) * K + skc;
  for (int k0 = 0; k0 < K; k0 += 32) {
    *(bf16x8*)&ldsA[srow][skc] = *(const bf16x8*)(Ag + k0);
    *(bf16x8*)&ldsB[srow][skc] = *(const bf16x8*)(Bg + k0);
    __syncthreads();
    bf16x8 af[2], bfv[2];
#pragma unroll
    for (int mi = 0; mi < 2; mi++) af[mi]  = *(const bf16x8*)&ldsA[wm + mi * 16 + lrow][lq * 8];
#pragma unroll
    for (int ni = 0; ni < 2; ni++) bfv[ni] = *(const bf16x8*)&ldsB[wn + ni * 16 + lrow][lq * 8];
#pragma unroll
    for (int mi = 0; mi < 2; mi++)
#pragma unroll
      for (int ni = 0; ni < 2; ni++)
        acc[mi][ni] = __builtin_amdgcn_mfma_f32_16x16x32_bf16(af[mi], bfv[ni], acc[mi][ni], 0, 0, 0);
    __syncthreads();
  }
#pragma unroll
  for (int mi = 0; mi < 2; mi++)
#pragma unroll
    for (int ni = 0; ni < 2; ni++) {
      int col = n0 + wn + ni * 16 + lrow;
#pragma unroll
      for (int r = 0; r < 4; r++) {
        int rowi = m0 + wm + mi * 16 + lq * 4 + r;
        float v = acc[mi][ni][r];
        if (BIAS) v += bias[col];
        if (ACT == 1) v = v / (1.f + __expf(-1.702f * v));   // GeLU2
        size_t idx = (size_t)rowi * N + col;
        if (RES) v += res[idx];
        if (OUTBF) ((bf16*)outp)[idx] = __float2bfloat16(v);
        else       ((float*)outp)[idx] = v;
      }
    }
}

// ---------------- fp32 flash attention (online softmax) ----------------
// grid: (16 q-tiles of 64, B*NH);  block 256 = 4 waves x 16 q-rows
__global__ __launch_bounds__(256) void attn_kernel(
    const float* __restrict__ q, const float* __restrict__ k,
    const float* __restrict__ v, bf16* __restrict__ a) {
  __shared__ float ldsK[64][80];
  __shared__ float ldsV[64][80];
  int qt = blockIdx.x;
  int bh = blockIdx.y;
  int b = bh >> 3, h = bh & 7;
  int tid = threadIdx.x, wave = tid >> 6, lane = tid & 63;
  int r = lane & 15, g = lane >> 4;          // 4 lanes per row, 20 dims each
  int qrow = qt * 64 + wave * 16 + r;
  const float* qbase = q + ((size_t)(b * S_LEN + qrow)) * CDIM + h * DKH;
  float qreg[20];
#pragma unroll
  for (int t5 = 0; t5 < 5; t5++) {
    int d = g * 20 + t5 * 4;
    float4 qv = make_float4(0.f, 0.f, 0.f, 0.f);
    if (d < DKH) qv = *(const float4*)&qbase[d];
    qreg[t5 * 4 + 0] = qv.x; qreg[t5 * 4 + 1] = qv.y;
    qreg[t5 * 4 + 2] = qv.z; qreg[t5 * 4 + 3] = qv.w;
  }
  float m = -1e30f, ssum = 0.f;
  float o[20];
#pragma unroll
  for (int i = 0; i < 20; i++) o[i] = 0.f;
  const float scale = 0.11785113019775793f;  // 1/sqrt(72)

  int srow = tid >> 2, scg = tid & 3;        // staging: 4 threads per key row
  for (int kt = 0; kt <= qt; kt++) {
    const float* kg = k + ((size_t)(b * S_LEN + kt * 64 + srow)) * CDIM + h * DKH;
    const float* vg = v + ((size_t)(b * S_LEN + kt * 64 + srow)) * CDIM + h * DKH;
#pragma unroll
    for (int t5 = 0; t5 < 5; t5++) {
      int d = scg * 20 + t5 * 4;
      float4 kv = make_float4(0.f, 0.f, 0.f, 0.f);
      float4 vv = make_float4(0.f, 0.f, 0.f, 0.f);
      if (d < DKH) { kv = *(const float4*)&kg[d]; vv = *(const float4*)&vg[d]; }
      *(float4*)&ldsK[srow][scg * 20 + t5 * 4] = kv;
      *(float4*)&ldsV[srow][scg * 20 + t5 * 4] = vv;
    }
    __syncthreads();
    for (int jj = 0; jj < 64; jj++) {
      int kgidx = kt * 64 + jj;
      const float4* kp = (const float4*)&ldsK[jj][g * 20];
      float s = 0.f;
#pragma unroll
      for (int t5 = 0; t5 < 5; t5++) {
        float4 kk = kp[t5];
        s += qreg[t5 * 4 + 0] * kk.x + qreg[t5 * 4 + 1] * kk.y +
             qreg[t5 * 4 + 2] * kk.z + qreg[t5 * 4 + 3] * kk.w;
      }
      s += __shfl_xor(s, 16);
      s += __shfl_xor(s, 32);
      s *= scale;
      if (kgidx <= qrow) {
        float mnew = fmaxf(m, s);
        float p = __expf(s - mnew);
        if (mnew > m) {
          float corr = __expf(m - mnew);
          ssum *= corr;
#pragma unroll
          for (int i = 0; i < 20; i++) o[i] *= corr;
        }
        m = mnew;
        ssum += p;
        const float4* vp = (const float4*)&ldsV[jj][g * 20];
#pragma unroll
        for (int t5 = 0; t5 < 5; t5++) {
          float4 vv = vp[t5];
          o[t5 * 4 + 0] += p * vv.x; o[t5 * 4 + 1] += p * vv.y;
          o[t5 * 4 + 2] += p * vv.z; o[t5 * 4 + 3] += p * vv.w;
        }
      }
    }
    __syncthreads();
  }
  float inv = 1.f / ssum;
  bf16* ab = a + ((size_t)(b * S_LEN + qrow)) * CDIM + h * DKH;
#pragma unroll
  for (int i = 0; i < 20; i++) {
    int d = g * 20 + i;
    if (d < DKH) ab[d] = __float2bfloat16(o[i] * inv);
  }
}

// ---------------- launch ----------------
extern "C" void kernel_launch(void* const* d_in, const int* in_sizes, int n_in,
                              void* d_out, int out_size, void* d_ws, size_t ws_size,
                              hipStream_t stream) {
  const float* x    = (const float*)d_in[0];
  const float* pos0 = (const float*)d_in[1];
  const float* pos1 = (const float*)d_in[2];
  const float* pos2 = (const float*)d_in[3];
  const float* ln1g = (const float*)d_in[4];
  const float* ln1b = (const float*)d_in[5];
  const float* wq   = (const float*)d_in[6];
  const float* wk   = (const float*)d_in[7];
  const float* wv   = (const float*)d_in[8];
  const float* wo   = (const float*)d_in[9];
  const float* wob  = (const float*)d_in[10];
  const float* ln2g = (const float*)d_in[11];
  const float* ln2b = (const float*)d_in[12];
  const float* w1   = (const float*)d_in[13];
  const float* b1   = (const float*)d_in[14];
  const float* w2   = (const float*)d_in[15];
  const float* b2   = (const float*)d_in[16];

  char* ws = (char*)d_ws;
  size_t off = 0;
  auto alloc = [&](size_t bytes) {
    char* p = ws + off;
    off += (bytes + 255) & ~(size_t)255;
    return p;
  };
  const size_t wsz  = (size_t)4 * CDIM * CDIM * sizeof(bf16);
  const size_t wsz2 = (size_t)4 * CDIM * FFDIM * sizeof(bf16);
  bf16* wqT = (bf16*)alloc(wsz);
  bf16* wkT = (bf16*)alloc(wsz);
  bf16* wvT = (bf16*)alloc(wsz);
  bf16* woT = (bf16*)alloc(wsz);
  bf16* w1T = (bf16*)alloc(wsz2);
  bf16* w2T = (bf16*)alloc(wsz2);
  bf16* hbuf = (bf16*)alloc((size_t)MROWS * CDIM * sizeof(bf16));
  bf16* abuf = (bf16*)alloc((size_t)MROWS * CDIM * sizeof(bf16));
  bf16* ubuf = (bf16*)alloc((size_t)MROWS * FFDIM * sizeof(bf16));
  float* qf  = (float*)alloc((size_t)MROWS * CDIM * sizeof(float));
  float* kf  = (float*)alloc((size_t)MROWS * CDIM * sizeof(float));
  float* vf  = (float*)alloc((size_t)MROWS * CDIM * sizeof(float));
  float* xf  = (float*)d_out;   // residual stream lives in d_out (fp32)

  transpose_cvt<<<dim3(18, 18, 4), 256, 0, stream>>>(wq, wqT, CDIM, CDIM);
  transpose_cvt<<<dim3(18, 18, 4), 256, 0, stream>>>(wk, wkT, CDIM, CDIM);
  transpose_cvt<<<dim3(18, 18, 4), 256, 0, stream>>>(wv, wvT, CDIM, CDIM);
  transpose_cvt<<<dim3(18, 18, 4), 256, 0, stream>>>(wo, woT, CDIM, CDIM);
  transpose_cvt<<<dim3(72, 18, 4), 256, 0, stream>>>(w1, w1T, CDIM, FFDIM);
  transpose_cvt<<<dim3(18, 72, 4), 256, 0, stream>>>(w2, w2T, FFDIM, CDIM);

  build_xf<<<2304, 256, 0, stream>>>(x, pos0, pos1, pos2, xf);

  for (int l = 0; l < 4; l++) {
    const size_t wo_off = (size_t)l * CDIM * CDIM;
    const size_t w1_off = (size_t)l * CDIM * FFDIM;
    ln_kernel<<<1024, 256, 0, stream>>>(xf, ln1g + l * CDIM, ln1b + l * CDIM, hbuf);
    gemm_kernel<false, false, 0, false><<<dim3(64, 9), 256, 0, stream>>>(
        hbuf, wqT + wo_off, nullptr, nullptr, qf, MROWS, CDIM, CDIM);
    gemm_kernel<false, false, 0, false><<<dim3(64, 9), 256, 0, stream>>>(
        hbuf, wkT + wo_off, nullptr, nullptr, kf, MROWS, CDIM, CDIM);
    gemm_kernel<false, false, 0, false><<<dim3(64, 9), 256, 0, stream>>>(
        hbuf, wvT + wo_off, nullptr, nullptr, vf, MROWS, CDIM, CDIM);
    attn_kernel<<<dim3(16, 32), 256, 0, stream>>>(qf, kf, vf, abuf);
    gemm_kernel<true, true, 0, false><<<dim3(64, 9), 256, 0, stream>>>(
        abuf, woT + wo_off, wob + l * CDIM, xf, xf, MROWS, CDIM, CDIM);
    ln_kernel<<<1024, 256, 0, stream>>>(xf, ln2g + l * CDIM, ln2b + l * CDIM, hbuf);
    gemm_kernel<true, false, 1, true><<<dim3(64, 36), 256, 0, stream>>>(
        hbuf, w1T + w1_off, b1 + l * FFDIM, nullptr, ubuf, MROWS, FFDIM, CDIM);
    gemm_kernel<true, true, 0, false><<<dim3(64, 9), 256, 0, stream>>>(
        ubuf, w2T + w1_off, b2 + l * CDIM, xf, xf, MROWS, CDIM, FFDIM);
  }
}

// Round 5
// 814.761 us; speedup vs baseline: 2.3788x; 2.3788x over previous
//
#include <hip/hip_runtime.h>
#include <hip/hip_bf16.h>

typedef __hip_bfloat16 bf16;
using bf16x8 = __attribute__((ext_vector_type(8))) short;
using f32x4  = __attribute__((ext_vector_type(4))) float;

#define S_LEN 1024
#define CDIM  576
#define NHEAD 8
#define DKH   72
#define BATCH 4
#define MROWS 4096   // B*S
#define FFDIM 2304

// ---------------- weight transpose + fp32->bf16 convert ----------------
// in: [L, K, N] fp32  ->  out: [L, N, K] bf16   (grid.z = L)
__global__ __launch_bounds__(256) void transpose_cvt(
    const float* __restrict__ in, bf16* __restrict__ out, int K, int N) {
  __shared__ float tile[32][33];
  const size_t mat = (size_t)K * N;
  const float* inl = in + (size_t)blockIdx.z * mat;
  bf16* outl = out + (size_t)blockIdx.z * mat;
  int n0 = blockIdx.x * 32, k0 = blockIdx.y * 32;
  int tx = threadIdx.x & 31, ty = threadIdx.x >> 5;   // ty 0..7
#pragma unroll
  for (int i = 0; i < 32; i += 8)
    tile[ty + i][tx] = inl[(size_t)(k0 + ty + i) * N + (n0 + tx)];
  __syncthreads();
#pragma unroll
  for (int i = 0; i < 32; i += 8)
    outl[(size_t)(n0 + ty + i) * K + (k0 + tx)] = __float2bfloat16(tile[tx][ty + i]);
}

// ---------------- xf = right_shift(x) + pos ----------------
__global__ __launch_bounds__(256) void build_xf(
    const float* __restrict__ x, const float* __restrict__ p0,
    const float* __restrict__ p1, const float* __restrict__ p2,
    float* __restrict__ xf) {
  int idx = blockIdx.x * 256 + threadIdx.x;      // one float4 per thread
  int c4 = idx % 144;
  int s  = (idx / 144) & (S_LEN - 1);
  int b  = idx / (144 * S_LEN);
  int c  = c4 * 4;
  int t = s >> 8, hh = (s >> 4) & 15, w = s & 15;
  float4 pv;
  if (c < 192)       pv = *(const float4*)&p0[t  * 192 + c];
  else if (c < 384)  pv = *(const float4*)&p1[hh * 192 + c - 192];
  else               pv = *(const float4*)&p2[w  * 192 + c - 384];
  float4 xv = make_float4(0.f, 0.f, 0.f, 0.f);
  if (s > 0) xv = *(const float4*)&x[((size_t)b * S_LEN + s - 1) * CDIM + c];
  float4 r = make_float4(xv.x + pv.x, xv.y + pv.y, xv.z + pv.z, xv.w + pv.w);
  *(float4*)&xf[((size_t)b * S_LEN + s) * CDIM + c] = r;
}

// ---------------- LayerNorm (eps added to rsqrt, per reference) ----------------
__global__ __launch_bounds__(256) void ln_kernel(
    const float* __restrict__ x, const float* __restrict__ g,
    const float* __restrict__ b, bf16* __restrict__ out) {
  int row  = blockIdx.x * 4 + (threadIdx.x >> 6);
  int lane = threadIdx.x & 63;
  const float* xr = x + (size_t)row * CDIM;
  float vals[9];
  float sum = 0.f;
#pragma unroll
  for (int i = 0; i < 9; i++) { vals[i] = xr[lane + 64 * i]; sum += vals[i]; }
#pragma unroll
  for (int o = 1; o < 64; o <<= 1) sum += __shfl_xor(sum, o);
  float mu = sum * (1.f / CDIM);
  float vs = 0.f;
#pragma unroll
  for (int i = 0; i < 9; i++) { float d = vals[i] - mu; vs += d * d; }
#pragma unroll
  for (int o = 1; o < 64; o <<= 1) vs += __shfl_xor(vs, o);
  float mult = 1e-5f + rsqrtf(vs * (1.f / CDIM));
  bf16* orow = out + (size_t)row * CDIM;
#pragma unroll
  for (int i = 0; i < 9; i++) {
    int c = lane + 64 * i;
    orow[c] = __float2bfloat16((vals[i] - mu) * mult * g[c] + b[c]);
  }
}

// ---------------- generic bf16 MFMA GEMM ----------------
// C[M,N] = act(A[M,K] @ Bt[N,K]^T + bias) (+ res);  out fp32 or bf16
template <bool BIAS, bool RES, int ACT, bool OUTBF>
__global__ __launch_bounds__(256) void gemm_kernel(
    const bf16* __restrict__ A, const bf16* __restrict__ Bt,
    const float* __restrict__ bias, const float* __restrict__ res,
    void* __restrict__ outp, int M, int N, int K) {
  __shared__ short ldsA[64][40];
  __shared__ short ldsB[64][40];
  int m0 = blockIdx.x * 64, n0 = blockIdx.y * 64;
  int tid = threadIdx.x;
  int wave = tid >> 6, lane = tid & 63;
  int wm = (wave & 1) * 32, wn = (wave >> 1) * 32;
  int lrow = lane & 15, lq = lane >> 4;
  f32x4 acc[2][2] = {};
  int srow = tid >> 2, skc = (tid & 3) * 8;
  const short* Ag = ((const short*)A) + (size_t)(m0 + srow) * K + skc;
  const short* Bg = ((const short*)Bt) + (size_t)(n0 + srow) * K + skc;
  for (int k0 = 0; k0 < K; k0 += 32) {
    *(bf16x8*)&ldsA[srow][skc] = *(const bf16x8*)(Ag + k0);
    *(bf16x8*)&ldsB[srow][skc] = *(const bf16x8*)(Bg + k0);
    __syncthreads();
    bf16x8 af[2], bfv[2];
#pragma unroll
    for (int mi = 0; mi < 2; mi++) af[mi]  = *(const bf16x8*)&ldsA[wm + mi * 16 + lrow][lq * 8];
#pragma unroll
    for (int ni = 0; ni < 2; ni++) bfv[ni] = *(const bf16x8*)&ldsB[wn + ni * 16 + lrow][lq * 8];
#pragma unroll
    for (int mi = 0; mi < 2; mi++)
#pragma unroll
      for (int ni = 0; ni < 2; ni++)
        acc[mi][ni] = __builtin_amdgcn_mfma_f32_16x16x32_bf16(af[mi], bfv[ni], acc[mi][ni], 0, 0, 0);
    __syncthreads();
  }
#pragma unroll
  for (int mi = 0; mi < 2; mi++)
#pragma unroll
    for (int ni = 0; ni < 2; ni++) {
      int col = n0 + wn + ni * 16 + lrow;
#pragma unroll
      for (int r = 0; r < 4; r++) {
        int rowi = m0 + wm + mi * 16 + lq * 4 + r;
        float v = acc[mi][ni][r];
        if (BIAS) v += bias[col];
        if (ACT == 1) v = v / (1.f + __expf(-1.702f * v));   // GeLU2
        size_t idx = (size_t)rowi * N + col;
        if (RES) v += res[idx];
        if (OUTBF) ((bf16*)outp)[idx] = __float2bfloat16(v);
        else       ((float*)outp)[idx] = v;
      }
    }
}

// float -> bf16 bits (RNE), pure integer math (type-safe for LDS punning)
__device__ __forceinline__ short f2bf_bits(float x) {
  unsigned int u = __float_as_uint(x);
  u += 0x7fffu + ((u >> 16) & 1u);
  return (short)(u >> 16);
}

// ---------------- MFMA flash attention ----------------
// grid: (8 qt-pairs, B*NH), block 256 = 4 waves x 16 q-rows.
// Block processes q-tiles {x, 15-x}: exactly 17 K-tiles each -> perfect balance.
// q,k,v: bf16 [B*S][C] per-head slices of width 72 (zero-padded to 96 in LDS).
__global__ __launch_bounds__(256) void attn_mfma(
    const bf16* __restrict__ q, const bf16* __restrict__ k,
    const bf16* __restrict__ v, bf16* __restrict__ a) {
  __shared__ short ldsK[64][104];    // [key][d], d padded to 96
  __shared__ short ldsVt[96][72];    // [d][key] (V transposed), key padded
  __shared__ short ldsP[4][16][72];  // per-wave P strip [q][key]
  int bh = blockIdx.y;
  int b = bh >> 3, h = bh & 7;
  int tid = threadIdx.x, wave = tid >> 6, lane = tid & 63;
  int lr = lane & 15, quad = lane >> 4;
  const float scale = 0.11785113019775793f;  // 1/sqrt(72)

  for (int half = 0; half < 2; half++) {
    int qt = half == 0 ? blockIdx.x : 15 - blockIdx.x;
    int qrow = qt * 64 + wave * 16 + lr;
    const short* qg = ((const short*)q) + ((size_t)(b * S_LEN + qrow)) * CDIM + h * DKH;
    bf16x8 qfrag[3];
#pragma unroll
    for (int c = 0; c < 3; c++) {
      int d0 = c * 32 + quad * 8;
      bf16x8 z = {0, 0, 0, 0, 0, 0, 0, 0};
      qfrag[c] = (d0 < DKH) ? *(const bf16x8*)(qg + d0) : z;
    }
    f32x4 oacc[6] = {};
    float m[4], l[4];
#pragma unroll
    for (int r = 0; r < 4; r++) { m[r] = -1e30f; l[r] = 0.f; }

    for (int kt = 0; kt <= qt; kt++) {
      __syncthreads();
      // ---- stage K (row-major) and V^T into LDS ----
      {
        int key = tid & 63;
        int dgb = tid >> 6;  // 0..3
        const short* kgr = ((const short*)k) + ((size_t)(b * S_LEN + kt * 64 + key)) * CDIM + h * DKH;
        const short* vgr = ((const short*)v) + ((size_t)(b * S_LEN + kt * 64 + key)) * CDIM + h * DKH;
#pragma unroll
        for (int pass = 0; pass < 3; pass++) {
          int d0 = (dgb + pass * 4) * 8;  // 0..88
          bf16x8 kv = {0, 0, 0, 0, 0, 0, 0, 0};
          bf16x8 vv = {0, 0, 0, 0, 0, 0, 0, 0};
          if (d0 < DKH) { kv = *(const bf16x8*)(kgr + d0); vv = *(const bf16x8*)(vgr + d0); }
          *(bf16x8*)&ldsK[key][d0] = kv;
#pragma unroll
          for (int j = 0; j < 8; j++) ldsVt[d0 + j][key] = vv[j];
        }
      }
      __syncthreads();
      // ---- S = Q K^T ----
      f32x4 sacc[4] = {};
#pragma unroll
      for (int nc = 0; nc < 4; nc++)
#pragma unroll
        for (int c = 0; c < 3; c++) {
          bf16x8 kf = *(const bf16x8*)&ldsK[nc * 16 + lr][c * 32 + quad * 8];
          sacc[nc] = __builtin_amdgcn_mfma_f32_16x16x32_bf16(qfrag[c], kf, sacc[nc], 0, 0, 0);
        }
      // ---- scale + causal mask + online softmax ----
      float tmax[4];
#pragma unroll
      for (int r = 0; r < 4; r++) tmax[r] = -1e30f;
      bool diag = (kt == qt);
#pragma unroll
      for (int nc = 0; nc < 4; nc++)
#pragma unroll
        for (int r = 0; r < 4; r++) {
          float s = sacc[nc][r] * scale;
          if (diag && (nc * 16 + lr > wave * 16 + quad * 4 + r)) s = -1e30f;
          sacc[nc][r] = s;
          tmax[r] = fmaxf(tmax[r], s);
        }
#pragma unroll
      for (int r = 0; r < 4; r++) {
        tmax[r] = fmaxf(tmax[r], __shfl_xor(tmax[r], 1));
        tmax[r] = fmaxf(tmax[r], __shfl_xor(tmax[r], 2));
        tmax[r] = fmaxf(tmax[r], __shfl_xor(tmax[r], 4));
        tmax[r] = fmaxf(tmax[r], __shfl_xor(tmax[r], 8));
      }
      float alpha[4], psum[4];
#pragma unroll
      for (int r = 0; r < 4; r++) {
        float mn = fmaxf(m[r], tmax[r]);
        alpha[r] = __expf(m[r] - mn);
        m[r] = mn;
        psum[r] = 0.f;
      }
#pragma unroll
      for (int nc = 0; nc < 4; nc++)
#pragma unroll
        for (int r = 0; r < 4; r++) {
          float p = __expf(sacc[nc][r] - m[r]);
          psum[r] += p;
          ldsP[wave][quad * 4 + r][nc * 16 + lr] = f2bf_bits(p);
        }
      // reduce row-sum across the 16 lanes holding this row's columns
#pragma unroll
      for (int r = 0; r < 4; r++) {
        psum[r] += __shfl_xor(psum[r], 1);
        psum[r] += __shfl_xor(psum[r], 2);
        psum[r] += __shfl_xor(psum[r], 4);
        psum[r] += __shfl_xor(psum[r], 8);
        l[r] = l[r] * alpha[r] + psum[r];
      }
#pragma unroll
      for (int dc = 0; dc < 6; dc++)
#pragma unroll
        for (int r = 0; r < 4; r++) oacc[dc][r] *= alpha[r];
      // pin program order: P stores above must precede P loads below
      __builtin_amdgcn_sched_barrier(0);
      // ---- O += P V (wave-local P read; same-wave DS ops execute in order) ----
      bf16x8 pfrag[2];
#pragma unroll
      for (int kc = 0; kc < 2; kc++)
        pfrag[kc] = *(const bf16x8*)&ldsP[wave][lr][kc * 32 + quad * 8];
#pragma unroll
      for (int dc = 0; dc < 6; dc++)
#pragma unroll
        for (int kc = 0; kc < 2; kc++) {
          bf16x8 vf = *(const bf16x8*)&ldsVt[dc * 16 + lr][kc * 32 + quad * 8];
          oacc[dc] = __builtin_amdgcn_mfma_f32_16x16x32_bf16(pfrag[kc], vf, oacc[dc], 0, 0, 0);
        }
    }  // kt

    // ---- epilogue: a[q][d] = O / l ----
#pragma unroll
    for (int dc = 0; dc < 6; dc++) {
      int d = dc * 16 + lr;
      if (d < DKH) {
#pragma unroll
        for (int r = 0; r < 4; r++) {
          int row = qt * 64 + wave * 16 + quad * 4 + r;
          float val = oacc[dc][r] / l[r];
          a[((size_t)(b * S_LEN + row)) * CDIM + h * DKH + d] = __float2bfloat16(val);
        }
      }
    }
  }  // half
}

// ---------------- launch ----------------
extern "C" void kernel_launch(void* const* d_in, const int* in_sizes, int n_in,
                              void* d_out, int out_size, void* d_ws, size_t ws_size,
                              hipStream_t stream) {
  const float* x    = (const float*)d_in[0];
  const float* pos0 = (const float*)d_in[1];
  const float* pos1 = (const float*)d_in[2];
  const float* pos2 = (const float*)d_in[3];
  const float* ln1g = (const float*)d_in[4];
  const float* ln1b = (const float*)d_in[5];
  const float* wq   = (const float*)d_in[6];
  const float* wk   = (const float*)d_in[7];
  const float* wv   = (const float*)d_in[8];
  const float* wo   = (const float*)d_in[9];
  const float* wob  = (const float*)d_in[10];
  const float* ln2g = (const float*)d_in[11];
  const float* ln2b = (const float*)d_in[12];
  const float* w1   = (const float*)d_in[13];
  const float* b1   = (const float*)d_in[14];
  const float* w2   = (const float*)d_in[15];
  const float* b2   = (const float*)d_in[16];

  char* ws = (char*)d_ws;
  size_t off = 0;
  auto alloc = [&](size_t bytes) {
    char* p = ws + off;
    off += (bytes + 255) & ~(size_t)255;
    return p;
  };
  const size_t wsz  = (size_t)4 * CDIM * CDIM * sizeof(bf16);
  const size_t wsz2 = (size_t)4 * CDIM * FFDIM * sizeof(bf16);
  bf16* wqT = (bf16*)alloc(wsz);
  bf16* wkT = (bf16*)alloc(wsz);
  bf16* wvT = (bf16*)alloc(wsz);
  bf16* woT = (bf16*)alloc(wsz);
  bf16* w1T = (bf16*)alloc(wsz2);
  bf16* w2T = (bf16*)alloc(wsz2);
  bf16* hbuf = (bf16*)alloc((size_t)MROWS * CDIM * sizeof(bf16));
  bf16* abuf = (bf16*)alloc((size_t)MROWS * CDIM * sizeof(bf16));
  bf16* ubuf = (bf16*)alloc((size_t)MROWS * FFDIM * sizeof(bf16));
  bf16* qb   = (bf16*)alloc((size_t)MROWS * CDIM * sizeof(bf16));
  bf16* kb   = (bf16*)alloc((size_t)MROWS * CDIM * sizeof(bf16));
  bf16* vb   = (bf16*)alloc((size_t)MROWS * CDIM * sizeof(bf16));
  float* xf  = (float*)d_out;   // residual stream lives in d_out (fp32)

  transpose_cvt<<<dim3(18, 18, 4), 256, 0, stream>>>(wq, wqT, CDIM, CDIM);
  transpose_cvt<<<dim3(18, 18, 4), 256, 0, stream>>>(wk, wkT, CDIM, CDIM);
  transpose_cvt<<<dim3(18, 18, 4), 256, 0, stream>>>(wv, wvT, CDIM, CDIM);
  transpose_cvt<<<dim3(18, 18, 4), 256, 0, stream>>>(wo, woT, CDIM, CDIM);
  transpose_cvt<<<dim3(72, 18, 4), 256, 0, stream>>>(w1, w1T, CDIM, FFDIM);
  transpose_cvt<<<dim3(18, 72, 4), 256, 0, stream>>>(w2, w2T, FFDIM, CDIM);

  build_xf<<<2304, 256, 0, stream>>>(x, pos0, pos1, pos2, xf);

  for (int l = 0; l < 4; l++) {
    const size_t wo_off = (size_t)l * CDIM * CDIM;
    const size_t w1_off = (size_t)l * CDIM * FFDIM;
    ln_kernel<<<1024, 256, 0, stream>>>(xf, ln1g + l * CDIM, ln1b + l * CDIM, hbuf);
    gemm_kernel<false, false, 0, true><<<dim3(64, 9), 256, 0, stream>>>(
        hbuf, wqT + wo_off, nullptr, nullptr, qb, MROWS, CDIM, CDIM);
    gemm_kernel<false, false, 0, true><<<dim3(64, 9), 256, 0, stream>>>(
        hbuf, wkT + wo_off, nullptr, nullptr, kb, MROWS, CDIM, CDIM);
    gemm_kernel<false, false, 0, true><<<dim3(64, 9), 256, 0, stream>>>(
        hbuf, wvT + wo_off, nullptr, nullptr, vb, MROWS, CDIM, CDIM);
    attn_mfma<<<dim3(8, 32), 256, 0, stream>>>(qb, kb, vb, abuf);
    gemm_kernel<true, true, 0, false><<<dim3(64, 9), 256, 0, stream>>>(
        abuf, woT + wo_off, wob + l * CDIM, xf, xf, MROWS, CDIM, CDIM);
    ln_kernel<<<1024, 256, 0, stream>>>(xf, ln2g + l * CDIM, ln2b + l * CDIM, hbuf);
    gemm_kernel<true, false, 1, true><<<dim3(64, 36), 256, 0, stream>>>(
        hbuf, w1T + w1_off, b1 + l * FFDIM, nullptr, ubuf, MROWS, FFDIM, CDIM);
    gemm_kernel<true, true, 0, false><<<dim3(64, 9), 256, 0, stream>>>(
        ubuf, w2T + w1_off, b2 + l * CDIM, xf, xf, MROWS, CDIM, FFDIM);
  }
}